// Round 4
// baseline (80.787 us; speedup 1.0000x reference)
//
#include <hip/hip_runtime.h>
#include <hip/hip_bf16.h>
#include <hip/hip_cooperative_groups.h>

#define BATCH    512
#define IN_WIDTH 4096
#define OUT_F    4096
#define FAN_IN   128
#define BCHUNK   16                  // batches per LDS-resident slice
#define NBG      (BATCH / BCHUNK)    // 32
#define OBLK     512                 // o-range per gather block
#define NOG      (OUT_F / OBLK)      // 8
#define NBLOCKS  256                 // = NOG * NBG, one per CU
#define NTHREADS 1024
#define LDSB     (IN_WIDTH * BCHUNK * 2)   // 128 KiB

typedef float v2f __attribute__((ext_vector_type(2)));

__global__ void __launch_bounds__(NTHREADS, 1)
k_fused(const float* __restrict__ input, const int* __restrict__ idx,
        const float* __restrict__ weight, const float* __restrict__ bias,
        uint16_t* __restrict__ inTg, uint2* __restrict__ pk,
        float* __restrict__ out) {
  extern __shared__ char lds[];
  const int t   = threadIdx.x;
  const int blk = blockIdx.x;

  // ============ Phase A1: transpose slice input -> inTg[bg][j][16] bf16 =====
  // block (bg = blk>>3, jt = (blk&7)*512): 16 batches x 512 j
  {
    float (*tile)[513] = reinterpret_cast<float (*)[513]>(lds);  // [16][513] f32, 32.8 KB
    const int bg = blk >> 3;
    const int jt = (blk & 7) * 512;
    const int jl = t & 511;
    const int bh = t >> 9;            // wave-uniform (512 = 8 waves)
#pragma unroll
    for (int r = 0; r < 8; ++r) {
      const int bl = r * 2 + bh;      // 0..15
      tile[bl][jl] = input[(size_t)(bg * BCHUNK + bl) * IN_WIDTH + jt + jl];
    }
    __syncthreads();
    // contiguous 16 KB bf16 region: dword d = jj*8 + bb/2
    uint32_t* dst = reinterpret_cast<uint32_t*>(inTg) +
                    ((size_t)bg * IN_WIDTH + jt) * (BCHUNK / 2);
#pragma unroll
    for (int k = 0; k < 4; ++k) {
      const int d  = t + k * 1024;    // 0..4095
      const int jj = d >> 3;
      const int bb = (d & 7) * 2;
      __hip_bfloat16 h0 = __float2bfloat16(tile[bb][jj]);
      __hip_bfloat16 h1 = __float2bfloat16(tile[bb + 1][jj]);
      dst[d] = (uint32_t)(*reinterpret_cast<uint16_t*>(&h0)) |
               ((uint32_t)(*reinterpret_cast<uint16_t*>(&h1)) << 16);
    }
  }
  // ============ Phase A2: pack idx+weight -> pk (uint2 {j, bits(w)}) ========
  {
    const int i = (blk * NTHREADS + t) * 2;
    uint4 e;
    e.x = (uint32_t)idx[i];
    e.y = __float_as_uint(weight[i]);
    e.z = (uint32_t)idx[i + 1];
    e.w = __float_as_uint(weight[i + 1]);
    *reinterpret_cast<uint4*>(pk + i) = e;
  }

  cooperative_groups::this_grid().sync();

  // ============ Phase B: stage slice + gather + FMA + direct out write ======
  {
    const int og = blk & 7;
    const int bg = blk >> 3;
    // stage 128 KB contiguous
    uint4* inS4 = reinterpret_cast<uint4*>(lds);
    const uint4* src =
        reinterpret_cast<const uint4*>(inTg + (size_t)bg * IN_WIDTH * BCHUNK);
#pragma unroll
    for (int i = 0; i < 8; ++i) inS4[i * 1024 + t] = src[i * 1024 + t];
    __syncthreads();

    const int wv = t >> 6;
    const int l  = t & 63;
    const int o  = og * OBLK + wv * 32 + (l >> 1);  // 32 o per wave, 2 lanes/o
    const int p  = l & 1;                           // batch half (8 of 16)
    const int p16 = p * 16;

    const uint4* __restrict__ pko =
        reinterpret_cast<const uint4*>(pk + (size_t)o * FAN_IN);  // 64 entries
    const float bz = bias[o];

    v2f a0 = {0.f, 0.f}, a1 = {0.f, 0.f}, a2 = {0.f, 0.f}, a3 = {0.f, 0.f};

    auto step = [&](uint32_t j, uint32_t wbits) {
      const uint4 v = *reinterpret_cast<const uint4*>(lds + j * 32 + p16);
      const float wf = __uint_as_float(wbits);
      v2f w2; w2[0] = wf; w2[1] = wf;
      v2f x0, x1, x2, x3;
      x0[0] = __uint_as_float(v.x << 16); x0[1] = __uint_as_float(v.x & 0xffff0000u);
      x1[0] = __uint_as_float(v.y << 16); x1[1] = __uint_as_float(v.y & 0xffff0000u);
      x2[0] = __uint_as_float(v.z << 16); x2[1] = __uint_as_float(v.z & 0xffff0000u);
      x3[0] = __uint_as_float(v.w << 16); x3[1] = __uint_as_float(v.w & 0xffff0000u);
      a0 += x0 * w2; a1 += x1 * w2; a2 += x2 * w2; a3 += x3 * w2;
    };

    // software-pipelined: compute chunk c while chunk c+1's pk loads fly
    uint4 q0 = pko[0], q1 = pko[1], q2 = pko[2], q3 = pko[3];
#pragma unroll 1
    for (int c = 0; c < 15; ++c) {
      const uint4 n0 = pko[c * 4 + 4];
      const uint4 n1 = pko[c * 4 + 5];
      const uint4 n2 = pko[c * 4 + 6];
      const uint4 n3 = pko[c * 4 + 7];
      step(q0.x, q0.y); step(q0.z, q0.w);
      step(q1.x, q1.y); step(q1.z, q1.w);
      step(q2.x, q2.y); step(q2.z, q2.w);
      step(q3.x, q3.y); step(q3.z, q3.w);
      q0 = n0; q1 = n1; q2 = n2; q3 = n3;
    }
    step(q0.x, q0.y); step(q0.z, q0.w);
    step(q1.x, q1.y); step(q1.z, q1.w);
    step(q2.x, q2.y); step(q2.z, q2.w);
    step(q3.x, q3.y); step(q3.z, q3.w);

    // out[b][o], b = bg*16 + p*8 + i  (wave: 2 x 128 B segments per store)
    const float r[8] = {a0[0], a0[1], a1[0], a1[1], a2[0], a2[1], a3[0], a3[1]};
    const size_t obase = (size_t)(bg * BCHUNK + p * 8) * OUT_F + o;
#pragma unroll
    for (int i = 0; i < 8; ++i) out[obase + (size_t)i * OUT_F] = r[i] + bz;
  }
}

extern "C" void kernel_launch(void* const* d_in, const int* in_sizes, int n_in,
                              void* d_out, int out_size, void* d_ws, size_t ws_size,
                              hipStream_t stream) {
  const float* input  = (const float*)d_in[0];   // [512][4096] f32
  const float* weight = (const float*)d_in[1];   // [4096][128] f32
  const float* bias   = (const float*)d_in[2];   // [4096]      f32
  const int*   idx    = (const int*)d_in[3];     // [4096][128] int32
  float* out = (float*)d_out;                    // [512][4096] f32

  // ws: inTg (bf16, 4 MB) | pk (uint2, 4 MB)
  uint16_t* inTg = (uint16_t*)d_ws;
  uint2*    pk   = (uint2*)((char*)d_ws + 4u * 1024 * 1024);

  void* args[] = {(void*)&input, (void*)&idx, (void*)&weight, (void*)&bias,
                  (void*)&inTg, (void*)&pk, (void*)&out};
  hipLaunchCooperativeKernel((void*)k_fused, dim3(NBLOCKS), dim3(NTHREADS),
                             args, (unsigned int)LDSB, stream);
}

// Round 5
// 67.378 us; speedup vs baseline: 1.1990x; 1.1990x over previous
//
#include <hip/hip_runtime.h>
#include <hip/hip_bf16.h>

#define BATCH    512
#define IN_WIDTH 4096
#define OUT_F    4096
#define FAN_IN   128
#define BCHUNK   16                 // batches per LDS-resident slice
#define NBG      (BATCH / BCHUNK)   // 32
#define OBLK     512                // o-range per gather block
#define NOG      (OUT_F / OBLK)     // 8

typedef float    v2f __attribute__((ext_vector_type(2)));
typedef uint32_t v4u __attribute__((ext_vector_type(4)));

// ---------------------------------------------------------------------------
// Kernel A: input[b][j] f32 -> inTg[bg][j][16] bf16  (chunk-major; gather
// kernel's 128 KB LDS stage is then one contiguous coalesced read)
// ---------------------------------------------------------------------------
__global__ __launch_bounds__(256) void k_transpose_in(const float* __restrict__ in,
                                                      uint16_t* __restrict__ inTg) {
  __shared__ float tile[32][33];
  const int jt = blockIdx.x * 32;
  const int bt = blockIdx.y * 32;
  const int tx = threadIdx.x;       // 0..31
  const int ty = threadIdx.y;       // 0..7
#pragma unroll
  for (int r = 0; r < 32; r += 8) {
    tile[ty + r][tx] = in[(size_t)(bt + ty + r) * IN_WIDTH + (jt + tx)];
  }
  __syncthreads();
#pragma unroll
  for (int r = 0; r < 32; r += 8) {
    const int b = bt + tx;
    const int j = jt + ty + r;
    __hip_bfloat16 hv = __float2bfloat16(tile[tx][ty + r]);
    inTg[((size_t)(b >> 4) * IN_WIDTH + j) * BCHUNK + (b & 15)] =
        *reinterpret_cast<const uint16_t*>(&hv);
  }
}

// ---------------------------------------------------------------------------
// Kernel P: pack idx+weight -> pk[o][f] = {j, bits(w)}
// ---------------------------------------------------------------------------
__global__ __launch_bounds__(256) void k_pack(const int* __restrict__ idx,
                                              const float* __restrict__ weight,
                                              uint2* __restrict__ pk) {
  const int i = blockIdx.x * 256 + threadIdx.x;
  uint2 e;
  e.x = (uint32_t)idx[i];
  e.y = __float_as_uint(weight[i]);
  pk[i] = e;
}

// ---------------------------------------------------------------------------
// Kernel B: LDS-staged gather, explicitly 8-deep pipelined.
// Block (og, bg): stage inTg[bg] (4096 rows x 16 batches bf16 = 128 KB), then
// each lane owns (o = og*512 + wv*32 + l/2, batch-half p = l&1):
//   128 ds_read_b128 row gathers, 8 in flight at all times (inline asm).
// Writes out[b][o] directly (no outT round trip).
// ---------------------------------------------------------------------------
__global__ __launch_bounds__(1024, 1) void k_gather_lds(const uint16_t* __restrict__ inTg,
                                                        const uint2* __restrict__ pk,
                                                        const float* __restrict__ bias,
                                                        float* __restrict__ out) {
  extern __shared__ char lds[];
  const int og = blockIdx.x;
  const int bg = blockIdx.y;
  const int t  = threadIdx.x;

  // ---- stage 128 KB, contiguous ----
  {
    const v4u* __restrict__ src =
        reinterpret_cast<const v4u*>(inTg + (size_t)bg * IN_WIDTH * BCHUNK);
    v4u* dst = reinterpret_cast<v4u*>(lds);
#pragma unroll
    for (int i = 0; i < 8; ++i) dst[i * 1024 + t] = src[i * 1024 + t];
  }
  __syncthreads();

  const int wv = t >> 6;
  const int l  = t & 63;
  const int o  = og * OBLK + wv * 32 + (l >> 1);  // 32 o per wave, 2 lanes/o
  const int p  = l & 1;                           // batch half (8 of 16)

  // LDS byte address base for this lane (AS3 offset; aperture low32 == offset)
  const uint32_t sb = (uint32_t)(size_t)lds + (uint32_t)(p * 16);

  const v4u* __restrict__ pko =
      reinterpret_cast<const v4u*>(pk + (size_t)o * FAN_IN);   // 64 f-pair entries

  v2f a0 = {0.f, 0.f}, a1 = {0.f, 0.f}, a2 = {0.f, 0.f}, a3 = {0.f, 0.f};

#define DSREAD(dst, jj) \
  asm volatile("ds_read_b128 %0, %1" : "=v"(dst) : "v"(sb + ((jj) << 5)))

#define CONSUME(v, wbits)                                              \
  do {                                                                 \
    const float wf_ = __uint_as_float(wbits);                          \
    v2f w2_; w2_[0] = wf_; w2_[1] = wf_;                               \
    v2f x0_, x1_, x2_, x3_;                                            \
    x0_[0] = __uint_as_float((v).x << 16);                             \
    x0_[1] = __uint_as_float((v).x & 0xffff0000u);                     \
    x1_[0] = __uint_as_float((v).y << 16);                             \
    x1_[1] = __uint_as_float((v).y & 0xffff0000u);                     \
    x2_[0] = __uint_as_float((v).z << 16);                             \
    x2_[1] = __uint_as_float((v).z & 0xffff0000u);                     \
    x3_[0] = __uint_as_float((v).w << 16);                             \
    x3_[1] = __uint_as_float((v).w & 0xffff0000u);                     \
    a0 += x0_ * w2_; a1 += x1_ * w2_; a2 += x2_ * w2_; a3 += x3_ * w2_;\
  } while (0)

#define HALF(qq0, qq1, qq2, qq3, nextchunk, more)                      \
  do {                                                                 \
    v4u v0, v1, v2, v3, v4, v5, v6, v7;                                \
    DSREAD(v0, qq0.x); DSREAD(v1, qq0.z);                              \
    DSREAD(v2, qq1.x); DSREAD(v3, qq1.z);                              \
    DSREAD(v4, qq2.x); DSREAD(v5, qq2.z);                              \
    DSREAD(v6, qq3.x); DSREAD(v7, qq3.z);                              \
    const uint32_t w0 = qq0.y, w1 = qq0.w, w2 = qq1.y, w3 = qq1.w;     \
    const uint32_t w4 = qq2.y, w5 = qq2.w, w6 = qq3.y, w7 = qq3.w;     \
    if (more) {                                                        \
      qq0 = pko[(nextchunk) * 4 + 0];                                  \
      qq1 = pko[(nextchunk) * 4 + 1];                                  \
      qq2 = pko[(nextchunk) * 4 + 2];                                  \
      qq3 = pko[(nextchunk) * 4 + 3];                                  \
    }                                                                  \
    asm volatile("s_waitcnt lgkmcnt(0)" ::: "memory");                 \
    __builtin_amdgcn_sched_barrier(0);                                 \
    CONSUME(v0, w0); CONSUME(v1, w1); CONSUME(v2, w2); CONSUME(v3, w3);\
    CONSUME(v4, w4); CONSUME(v5, w5); CONSUME(v6, w6); CONSUME(v7, w7);\
  } while (0)

  // chunk = 4 v4u entries = 8 f-steps; 16 chunks total. Ping-pong qa/qb,
  // each half prefetches its buffer's chunk-after-next before the wait.
  v4u qa0 = pko[0], qa1 = pko[1], qa2 = pko[2], qa3 = pko[3];
  v4u qb0 = pko[4], qb1 = pko[5], qb2 = pko[6], qb3 = pko[7];

#pragma unroll 1
  for (int c = 0; c < 8; ++c) {
    HALF(qa0, qa1, qa2, qa3, 2 * c + 2, (c < 7));
    HALF(qb0, qb1, qb2, qb3, 2 * c + 3, (c < 7));
  }

  const float bz = bias[o];
  const float r[8] = {a0[0], a0[1], a1[0], a1[1], a2[0], a2[1], a3[0], a3[1]};
  // out[b][o], b = bg*16 + p*8 + i ; per store instr a wave covers 2 x 128 B
  const size_t obase = (size_t)(bg * BCHUNK + p * 8) * OUT_F + o;
#pragma unroll
  for (int i = 0; i < 8; ++i) out[obase + (size_t)i * OUT_F] = r[i] + bz;

#undef HALF
#undef CONSUME
#undef DSREAD
}

extern "C" void kernel_launch(void* const* d_in, const int* in_sizes, int n_in,
                              void* d_out, int out_size, void* d_ws, size_t ws_size,
                              hipStream_t stream) {
  const float* input  = (const float*)d_in[0];   // [512][4096] f32
  const float* weight = (const float*)d_in[1];   // [4096][128] f32
  const float* bias   = (const float*)d_in[2];   // [4096]      f32
  const int*   idx    = (const int*)d_in[3];     // [4096][128] int32
  float* out = (float*)d_out;                    // [512][4096] f32

  // ws: inTg (bf16, 4 MB) | pk (uint2, 4 MB)
  uint16_t* inTg = (uint16_t*)d_ws;
  uint2*    pk   = (uint2*)((char*)d_ws + 4u * 1024 * 1024);

  dim3 tblk(32, 8);
  k_transpose_in<<<dim3(IN_WIDTH / 32, BATCH / 32), tblk, 0, stream>>>(input, inTg);
  k_pack<<<dim3(OUT_F * FAN_IN / 256), dim3(256), 0, stream>>>(idx, weight, pk);
  k_gather_lds<<<dim3(NOG, NBG), dim3(1024), IN_WIDTH * BCHUNK * 2, stream>>>(
      inTg, pk, bias, out);
}

// Round 6
// 39.491 us; speedup vs baseline: 2.0457x; 1.7062x over previous
//
#include <hip/hip_runtime.h>
#include <hip/hip_bf16.h>

#define BATCH    512
#define IN_WIDTH 4096
#define OUT_F    4096
#define FAN_IN   128
#define BCHUNK   16                 // batches per LDS-resident slice
#define NBG      (BATCH / BCHUNK)   // 32
#define OBLK     512                // o-range per gather block
#define NOG      (OUT_F / OBLK)     // 8

typedef float    v2f __attribute__((ext_vector_type(2)));
typedef uint32_t v4u __attribute__((ext_vector_type(4)));

// ---------------------------------------------------------------------------
// Kernel A: input[b][j] f32 -> inTg[bg][j][16] bf16 (chunk-major)
// ---------------------------------------------------------------------------
__global__ __launch_bounds__(256) void k_transpose_in(const float* __restrict__ in,
                                                      uint16_t* __restrict__ inTg) {
  __shared__ float tile[32][33];
  const int jt = blockIdx.x * 32;
  const int bt = blockIdx.y * 32;
  const int tx = threadIdx.x;       // 0..31
  const int ty = threadIdx.y;       // 0..7
#pragma unroll
  for (int r = 0; r < 32; r += 8) {
    tile[ty + r][tx] = in[(size_t)(bt + ty + r) * IN_WIDTH + (jt + tx)];
  }
  __syncthreads();
#pragma unroll
  for (int r = 0; r < 32; r += 8) {
    const int b = bt + tx;
    const int j = jt + ty + r;
    __hip_bfloat16 hv = __float2bfloat16(tile[tx][ty + r]);
    inTg[((size_t)(b >> 4) * IN_WIDTH + j) * BCHUNK + (b & 15)] =
        *reinterpret_cast<const uint16_t*>(&hv);
  }
}

// ---------------------------------------------------------------------------
// Kernel P: pack idx+weight -> pk[o][f] = {j, bits(w)}
// ---------------------------------------------------------------------------
__global__ __launch_bounds__(256) void k_pack(const int* __restrict__ idx,
                                              const float* __restrict__ weight,
                                              uint2* __restrict__ pk) {
  const int i = blockIdx.x * 256 + threadIdx.x;
  uint2 e;
  e.x = (uint32_t)idx[i];
  e.y = __float_as_uint(weight[i]);
  pk[i] = e;
}

// ---------------------------------------------------------------------------
// Kernel B: LDS-staged gather, depth-4 rotating pipeline w/ counted lgkmcnt.
// Block (og, bg): stage 128 KB slice; lane owns (o, batch-half p).
// 128 ds_read_b128 row gathers per lane; 4-8 kept in flight at all times.
// ---------------------------------------------------------------------------
__global__ __launch_bounds__(1024, 4) void k_gather_lds(const uint16_t* __restrict__ inTg,
                                                        const uint2* __restrict__ pk,
                                                        const float* __restrict__ bias,
                                                        float* __restrict__ out) {
  extern __shared__ char lds[];
  const int og = blockIdx.x;
  const int bg = blockIdx.y;
  const int t  = threadIdx.x;

  // ---- stage 128 KB, contiguous ----
  {
    const v4u* __restrict__ src =
        reinterpret_cast<const v4u*>(inTg + (size_t)bg * IN_WIDTH * BCHUNK);
    v4u* dst = reinterpret_cast<v4u*>(lds);
#pragma unroll
    for (int i = 0; i < 8; ++i) dst[i * 1024 + t] = src[i * 1024 + t];
  }
  __syncthreads();

  const int wv = t >> 6;
  const int l  = t & 63;
  const int o  = og * OBLK + wv * 32 + (l >> 1);  // 32 o per wave, 2 lanes/o
  const int p  = l & 1;                           // batch half (8 of 16)

  // LDS byte address base (validated in R5: low-32 of aperture addr works)
  const uint32_t sb = (uint32_t)(size_t)lds + (uint32_t)(p * 16);

  const v4u* __restrict__ pko =
      reinterpret_cast<const v4u*>(pk + (size_t)o * FAN_IN);   // 64 entries = 128 f

  v2f a0 = {0.f, 0.f}, a1 = {0.f, 0.f}, a2 = {0.f, 0.f}, a3 = {0.f, 0.f};

#define DSREAD(d, jj) \
  asm volatile("ds_read_b128 %0, %1" : "=v"(d) : "v"(sb + ((jj) << 5)))

#define WAIT4() do { asm volatile("s_waitcnt lgkmcnt(4)" ::: "memory"); \
                     __builtin_amdgcn_sched_barrier(0); } while (0)
#define WAIT0() do { asm volatile("s_waitcnt lgkmcnt(0)" ::: "memory"); \
                     __builtin_amdgcn_sched_barrier(0); } while (0)

#define CONSUME(v, wbits)                                              \
  do {                                                                 \
    const float wf_ = __uint_as_float(wbits);                          \
    v2f w2_; w2_[0] = wf_; w2_[1] = wf_;                               \
    v2f x0_, x1_, x2_, x3_;                                            \
    x0_[0] = __uint_as_float((v).x << 16);                             \
    x0_[1] = __uint_as_float((v).x & 0xffff0000u);                     \
    x1_[0] = __uint_as_float((v).y << 16);                             \
    x1_[1] = __uint_as_float((v).y & 0xffff0000u);                     \
    x2_[0] = __uint_as_float((v).z << 16);                             \
    x2_[1] = __uint_as_float((v).z & 0xffff0000u);                     \
    x3_[0] = __uint_as_float((v).w << 16);                             \
    x3_[1] = __uint_as_float((v).w & 0xffff0000u);                     \
    a0 += x0_ * w2_; a1 += x1_ * w2_; a2 += x2_ * w2_; a3 += x3_ * w2_;\
  } while (0)

  // 32 groups of 4 f-steps. Two slots (A/B); issuing a slot leaves the other
  // slot's 4 reads outstanding -> lgkmcnt(4) frees the older slot.
  uint4 q0 = *(const uint4*)(pko + 0), q1 = *(const uint4*)(pko + 1);
  uint4 q2 = *(const uint4*)(pko + 2), q3 = *(const uint4*)(pko + 3);
  v4u vA0, vA1, vA2, vA3, vB0, vB1, vB2, vB3;
  uint32_t wA0, wA1, wA2, wA3, wB0, wB1, wB2, wB3;

  // prologue: issue group 0 (A) from q0,q1
  DSREAD(vA0, q0.x); DSREAD(vA1, q0.z); DSREAD(vA2, q1.x); DSREAD(vA3, q1.z);
  wA0 = q0.y; wA1 = q0.w; wA2 = q1.y; wA3 = q1.w;

#pragma unroll 1
  for (int c = 0; c < 15; ++c) {
    // issue B = group 2c+1 from q2,q3  (8 outstanding after this)
    DSREAD(vB0, q2.x); DSREAD(vB1, q2.z); DSREAD(vB2, q3.x); DSREAD(vB3, q3.z);
    wB0 = q2.y; wB1 = q2.w; wB2 = q3.y; wB3 = q3.w;
    q0 = *(const uint4*)(pko + 4 * c + 4);   // group 2c+2
    q1 = *(const uint4*)(pko + 4 * c + 5);
    WAIT4();                                  // A done, B in flight
    CONSUME(vA0, wA0); CONSUME(vA1, wA1); CONSUME(vA2, wA2); CONSUME(vA3, wA3);
    // issue A = group 2c+2 from q0,q1
    DSREAD(vA0, q0.x); DSREAD(vA1, q0.z); DSREAD(vA2, q1.x); DSREAD(vA3, q1.z);
    wA0 = q0.y; wA1 = q0.w; wA2 = q1.y; wA3 = q1.w;
    q2 = *(const uint4*)(pko + 4 * c + 6);   // group 2c+3
    q3 = *(const uint4*)(pko + 4 * c + 7);
    WAIT4();                                  // B done, A in flight
    CONSUME(vB0, wB0); CONSUME(vB1, wB1); CONSUME(vB2, wB2); CONSUME(vB3, wB3);
  }
  // epilogue: A holds group 30; q2,q3 hold group 31
  DSREAD(vB0, q2.x); DSREAD(vB1, q2.z); DSREAD(vB2, q3.x); DSREAD(vB3, q3.z);
  wB0 = q2.y; wB1 = q2.w; wB2 = q3.y; wB3 = q3.w;
  WAIT4();
  CONSUME(vA0, wA0); CONSUME(vA1, wA1); CONSUME(vA2, wA2); CONSUME(vA3, wA3);
  WAIT0();
  CONSUME(vB0, wB0); CONSUME(vB1, wB1); CONSUME(vB2, wB2); CONSUME(vB3, wB3);

  const float bz = bias[o];
  const float r[8] = {a0[0], a0[1], a1[0], a1[1], a2[0], a2[1], a3[0], a3[1]};
  // out[b][o], b = bg*16 + p*8 + i ; wave covers 2 x 128 B segments per store
  const size_t obase = (size_t)(bg * BCHUNK + p * 8) * OUT_F + o;
#pragma unroll
  for (int i = 0; i < 8; ++i) out[obase + (size_t)i * OUT_F] = r[i] + bz;

#undef CONSUME
#undef WAIT4
#undef WAIT0
#undef DSREAD
}

extern "C" void kernel_launch(void* const* d_in, const int* in_sizes, int n_in,
                              void* d_out, int out_size, void* d_ws, size_t ws_size,
                              hipStream_t stream) {
  const float* input  = (const float*)d_in[0];   // [512][4096] f32
  const float* weight = (const float*)d_in[1];   // [4096][128] f32
  const float* bias   = (const float*)d_in[2];   // [4096]      f32
  const int*   idx    = (const int*)d_in[3];     // [4096][128] int32
  float* out = (float*)d_out;                    // [512][4096] f32

  // ws: inTg (bf16, 4 MB) | pk (uint2, 4 MB)
  uint16_t* inTg = (uint16_t*)d_ws;
  uint2*    pk   = (uint2*)((char*)d_ws + 4u * 1024 * 1024);

  dim3 tblk(32, 8);
  k_transpose_in<<<dim3(IN_WIDTH / 32, BATCH / 32), tblk, 0, stream>>>(input, inTg);
  k_pack<<<dim3(OUT_F * FAN_IN / 256), dim3(256), 0, stream>>>(idx, weight, pk);
  k_gather_lds<<<dim3(NOG, NBG), dim3(1024), IN_WIDTH * BCHUNK * 2, stream>>>(
      inTg, pk, bias, out);
}

// Round 7
// 37.794 us; speedup vs baseline: 2.1376x; 1.0449x over previous
//
#include <hip/hip_runtime.h>
#include <hip/hip_bf16.h>

#define BATCH    512
#define IN_WIDTH 4096
#define OUT_F    4096
#define FAN_IN   128
#define BCHUNK   16                 // batches per LDS-resident slice
#define NBG      (BATCH / BCHUNK)   // 32
#define OBLK     512                // o-range per gather block
#define NOG      (OUT_F / OBLK)     // 8

typedef float    v2f __attribute__((ext_vector_type(2)));
typedef uint32_t v4u __attribute__((ext_vector_type(4)));

// ---------------------------------------------------------------------------
// Kernel A: input[b][j] f32 -> inTg[bg][j][16] bf16 (chunk-major)
// ---------------------------------------------------------------------------
__global__ __launch_bounds__(256) void k_transpose_in(const float* __restrict__ in,
                                                      uint16_t* __restrict__ inTg) {
  __shared__ float tile[32][33];
  const int jt = blockIdx.x * 32;
  const int bt = blockIdx.y * 32;
  const int tx = threadIdx.x;       // 0..31
  const int ty = threadIdx.y;       // 0..7
#pragma unroll
  for (int r = 0; r < 32; r += 8) {
    tile[ty + r][tx] = in[(size_t)(bt + ty + r) * IN_WIDTH + (jt + tx)];
  }
  __syncthreads();
#pragma unroll
  for (int r = 0; r < 32; r += 8) {
    const int b = bt + tx;
    const int j = jt + ty + r;
    __hip_bfloat16 hv = __float2bfloat16(tile[tx][ty + r]);
    inTg[((size_t)(b >> 4) * IN_WIDTH + j) * BCHUNK + (b & 15)] =
        *reinterpret_cast<const uint16_t*>(&hv);
  }
}

// ---------------------------------------------------------------------------
// Kernel P: pack idx+weight -> pk[o][f] = {j, bits(w)}
// ---------------------------------------------------------------------------
__global__ __launch_bounds__(256) void k_pack(const int* __restrict__ idx,
                                              const float* __restrict__ weight,
                                              uint2* __restrict__ pk) {
  const int i = blockIdx.x * 256 + threadIdx.x;
  uint2 e;
  e.x = (uint32_t)idx[i];
  e.y = __float_as_uint(weight[i]);
  pk[i] = e;
}

// ---------------------------------------------------------------------------
// Kernel B: LDS-staged gather. DS pipeline depth 4 (counted lgkmcnt), and a
// 4-slot rotating prefetch of pk metadata: group c+4's {j,w} loads issue at
// iteration c (~3 iters ≈ 300+ cyc ahead of use) so ds_read issue never
// stalls on vmcnt. Group = 2 uint4 pk entries = 4 f-steps; 32 groups.
// ---------------------------------------------------------------------------
__global__ __launch_bounds__(1024, 4) void k_gather_lds(const uint16_t* __restrict__ inTg,
                                                        const uint2* __restrict__ pk,
                                                        const float* __restrict__ bias,
                                                        float* __restrict__ out) {
  extern __shared__ char lds[];
  const int og = blockIdx.x;
  const int bg = blockIdx.y;
  const int t  = threadIdx.x;

  // ---- stage 128 KB, contiguous ----
  {
    const v4u* __restrict__ src =
        reinterpret_cast<const v4u*>(inTg + (size_t)bg * IN_WIDTH * BCHUNK);
    v4u* dst = reinterpret_cast<v4u*>(lds);
#pragma unroll
    for (int i = 0; i < 8; ++i) dst[i * 1024 + t] = src[i * 1024 + t];
  }
  __syncthreads();

  const int wv = t >> 6;
  const int l  = t & 63;
  const int o  = og * OBLK + wv * 32 + (l >> 1);  // 32 o per wave, 2 lanes/o
  const int p  = l & 1;                           // batch half (8 of 16)

  const uint32_t sb = (uint32_t)(size_t)lds + (uint32_t)(p * 16);

  const uint4* __restrict__ pko =
      reinterpret_cast<const uint4*>(pk + (size_t)o * FAN_IN);   // 64 entries

  v2f a0 = {0.f, 0.f}, a1 = {0.f, 0.f}, a2 = {0.f, 0.f}, a3 = {0.f, 0.f};

#define DSREAD(d, jj) \
  asm volatile("ds_read_b128 %0, %1" : "=v"(d) : "v"(sb + ((jj) << 5)))

#define WAIT4() do { asm volatile("s_waitcnt lgkmcnt(4)" ::: "memory"); \
                     __builtin_amdgcn_sched_barrier(0); } while (0)
#define WAIT0() do { asm volatile("s_waitcnt lgkmcnt(0)" ::: "memory"); \
                     __builtin_amdgcn_sched_barrier(0); } while (0)

#define CONSUME(v, wbits)                                              \
  do {                                                                 \
    const float wf_ = __uint_as_float(wbits);                          \
    v2f w2_; w2_[0] = wf_; w2_[1] = wf_;                               \
    v2f x0_, x1_, x2_, x3_;                                            \
    x0_[0] = __uint_as_float((v).x << 16);                             \
    x0_[1] = __uint_as_float((v).x & 0xffff0000u);                     \
    x1_[0] = __uint_as_float((v).y << 16);                             \
    x1_[1] = __uint_as_float((v).y & 0xffff0000u);                     \
    x2_[0] = __uint_as_float((v).z << 16);                             \
    x2_[1] = __uint_as_float((v).z & 0xffff0000u);                     \
    x3_[0] = __uint_as_float((v).w << 16);                             \
    x3_[1] = __uint_as_float((v).w & 0xffff0000u);                     \
    a0 += x0_ * w2_; a1 += x1_ * w2_; a2 += x2_ * w2_; a3 += x3_ * w2_;\
  } while (0)

  // q slots: slot s holds pk group g with g % 4 == s. Refill slot c%4 with
  // group c+4 at iteration c; w's are copied out at issue time so refill
  // can't clobber live data.
  uint4 q0a = pko[0], q0b = pko[1];   // g0
  uint4 q1a = pko[2], q1b = pko[3];   // g1
  uint4 q2a = pko[4], q2b = pko[5];   // g2
  uint4 q3a = pko[6], q3b = pko[7];   // g3

  v4u vA0, vA1, vA2, vA3, vB0, vB1, vB2, vB3;
  uint32_t wA0, wA1, wA2, wA3, wB0, wB1, wB2, wB3;

  // prologue: issue g0 (buffer A) from slot 0
  DSREAD(vA0, q0a.x); DSREAD(vA1, q0a.z); DSREAD(vA2, q0b.x); DSREAD(vA3, q0b.z);
  wA0 = q0a.y; wA1 = q0a.w; wA2 = q0b.y; wA3 = q0b.w;

  // STEP(c): issue g(c+1) from slot (c+1)%4 into the other buffer, copy w's,
  // refill slot c%4 <- group min(c+4,31), WAIT4, consume buffer with g(c).
#define STEP(Cc, QI0, QI1, QR0, QR1,                                   \
             VC0, VC1, VC2, VC3, WC0, WC1, WC2, WC3,                   \
             VI0, VI1, VI2, VI3, WI0, WI1, WI2, WI3)                   \
  do {                                                                 \
    DSREAD(VI0, QI0.x); DSREAD(VI1, QI0.z);                            \
    DSREAD(VI2, QI1.x); DSREAD(VI3, QI1.z);                            \
    WI0 = QI0.y; WI1 = QI0.w; WI2 = QI1.y; WI3 = QI1.w;                \
    {                                                                  \
      const int gn_ = ((Cc) + 4 > 31) ? 31 : ((Cc) + 4);               \
      QR0 = pko[2 * gn_];                                              \
      QR1 = pko[2 * gn_ + 1];                                          \
    }                                                                  \
    WAIT4();                                                           \
    CONSUME(VC0, WC0); CONSUME(VC1, WC1);                              \
    CONSUME(VC2, WC2); CONSUME(VC3, WC3);                              \
  } while (0)

#define STEP_A(Cc, QI0, QI1, QR0, QR1) /* consume A (even c), issue B */ \
  STEP(Cc, QI0, QI1, QR0, QR1,                                           \
       vA0, vA1, vA2, vA3, wA0, wA1, wA2, wA3,                           \
       vB0, vB1, vB2, vB3, wB0, wB1, wB2, wB3)
#define STEP_B(Cc, QI0, QI1, QR0, QR1) /* consume B (odd c), issue A */  \
  STEP(Cc, QI0, QI1, QR0, QR1,                                           \
       vB0, vB1, vB2, vB3, wB0, wB1, wB2, wB3,                           \
       vA0, vA1, vA2, vA3, wA0, wA1, wA2, wA3)

#pragma unroll 1
  for (int cb = 0; cb < 28; cb += 4) {
    STEP_A(cb + 0, q1a, q1b, q0a, q0b);
    STEP_B(cb + 1, q2a, q2b, q1a, q1b);
    STEP_A(cb + 2, q3a, q3b, q2a, q2b);
    STEP_B(cb + 3, q0a, q0b, q3a, q3b);
  }
  STEP_A(28, q1a, q1b, q0a, q0b);
  STEP_B(29, q2a, q2b, q1a, q1b);
  STEP_A(30, q3a, q3b, q2a, q2b);
  // after c=30: A consumed g30, B holds g31 in flight
  WAIT0();
  CONSUME(vB0, wB0); CONSUME(vB1, wB1); CONSUME(vB2, wB2); CONSUME(vB3, wB3);

  const float bz = bias[o];
  const float r[8] = {a0[0], a0[1], a1[0], a1[1], a2[0], a2[1], a3[0], a3[1]};
  // out[b][o], b = bg*16 + p*8 + i ; wave covers 2 x 128 B segments per store
  const size_t obase = (size_t)(bg * BCHUNK + p * 8) * OUT_F + o;
#pragma unroll
  for (int i = 0; i < 8; ++i) out[obase + (size_t)i * OUT_F] = r[i] + bz;

#undef STEP_B
#undef STEP_A
#undef STEP
#undef CONSUME
#undef WAIT4
#undef WAIT0
#undef DSREAD
}

extern "C" void kernel_launch(void* const* d_in, const int* in_sizes, int n_in,
                              void* d_out, int out_size, void* d_ws, size_t ws_size,
                              hipStream_t stream) {
  const float* input  = (const float*)d_in[0];   // [512][4096] f32
  const float* weight = (const float*)d_in[1];   // [4096][128] f32
  const float* bias   = (const float*)d_in[2];   // [4096]      f32
  const int*   idx    = (const int*)d_in[3];     // [4096][128] int32
  float* out = (float*)d_out;                    // [512][4096] f32

  // ws: inTg (bf16, 4 MB) | pk (uint2, 4 MB)
  uint16_t* inTg = (uint16_t*)d_ws;
  uint2*    pk   = (uint2*)((char*)d_ws + 4u * 1024 * 1024);

  dim3 tblk(32, 8);
  k_transpose_in<<<dim3(IN_WIDTH / 32, BATCH / 32), tblk, 0, stream>>>(input, inTg);
  k_pack<<<dim3(OUT_F * FAN_IN / 256), dim3(256), 0, stream>>>(idx, weight, pk);
  k_gather_lds<<<dim3(NOG, NBG), dim3(1024), IN_WIDTH * BCHUNK * 2, stream>>>(
      inTg, pk, bias, out);
}